// Round 6
// baseline (336.796 us; speedup 1.0000x reference)
//
#include <hip/hip_runtime.h>
#include <hip/hip_bf16.h>

typedef __bf16 bf16;
typedef __bf16 bf16x8 __attribute__((ext_vector_type(8)));
typedef float f32x4 __attribute__((ext_vector_type(4)));

// (1/16) * log2(e): softmax scale folded into exp2
#define SM_C 0.09016994374947424f

// ---------------------------------------------------------------------------
// prep 1: X f32 -> bf16 (into first 16 MB of d_out; dead before final write)
// ---------------------------------------------------------------------------
__global__ __launch_bounds__(256) void cvt_x(
    const float* __restrict__ X, bf16* __restrict__ Xb)
{
    int i = blockIdx.x * 256 + threadIdx.x;   // 4096 * 256 threads
    const float* p = X + (size_t)i * 8;
    f32x4 a = *(const f32x4*)p, b = *(const f32x4*)(p + 4);
    bf16x8 r;
#pragma unroll
    for (int j = 0; j < 4; ++j) { r[j] = (bf16)a[j]; r[j + 4] = (bf16)b[j]; }
    *(bf16x8*)(Xb + (size_t)i * 8) = r;
}

// ---------------------------------------------------------------------------
// prep 2: W [k][n] f32 -> Wt[mat][n][k] bf16, tiled via LDS.
// ---------------------------------------------------------------------------
__global__ __launch_bounds__(256) void transpose_w(
    const float* __restrict__ Wq, const float* __restrict__ Wk,
    const float* __restrict__ Wv, const float* __restrict__ Wo,
    bf16* __restrict__ Wt)
{
    __shared__ bf16 Ls[64][72];
    const int m = blockIdx.y;
    const int tk = (blockIdx.x >> 2) * 64, tn = (blockIdx.x & 3) * 64;
    const float* W = (m == 0) ? Wq : (m == 1) ? Wk : (m == 2) ? Wv : Wo;
    const int t = threadIdx.x;
    const int col = (t & 15) * 4, row = t >> 4;
#pragma unroll
    for (int p = 0; p < 4; ++p) {
        f32x4 v = *(const f32x4*)(W + (size_t)(tk + row + p * 16) * 256 + tn + col);
#pragma unroll
        for (int i = 0; i < 4; ++i) Ls[row + p * 16][col + i] = (bf16)v[i];
    }
    __syncthreads();
    const int kc = (t & 7) * 8, nr = t >> 3;
#pragma unroll
    for (int p = 0; p < 2; ++p) {
        bf16x8 r;
#pragma unroll
        for (int i = 0; i < 8; ++i) r[i] = Ls[kc + i][nr + p * 32];
        *(bf16x8*)(Wt + (size_t)m * 65536 + (size_t)(tn + nr + p * 32) * 256 + tk + kc) = r;
    }
}

// ---------------------------------------------------------------------------
// 128x128-tile GEMM core: 4 waves, each computing a 64x64 quadrant as 4x4
// 16x16 frags (a-frag + b-frag reads amortize over 16 MFMAs).
// Used for both qkv (bf16 out, V transposed) and oproj (f32 out).
// ---------------------------------------------------------------------------
template <int OUT_F32>
__device__ void gemm128_body(
    const bf16* __restrict__ Xsrc, const bf16* __restrict__ Wsrc,
    const float* __restrict__ bias, int bm, int bn,
    void* __restrict__ out, int vmode)
{
    __shared__ bf16 Xs[128 * 72];
    __shared__ bf16 Ws[128 * 72];

    const int t    = threadIdx.x;
    const int lane = t & 63, wv = t >> 6;
    const int quad = lane >> 4, l16 = lane & 15;
    const int rh = (wv >> 1) * 64;    // row-half of this wave
    const int ch = (wv & 1) * 64;     // col-half

    const f32x4 zero = {0.0f, 0.0f, 0.0f, 0.0f};
    f32x4 acc[4][4];
#pragma unroll
    for (int i = 0; i < 4; ++i)
        for (int j = 0; j < 4; ++j) acc[i][j] = zero;

    const int sm = t >> 1;            // 0..127 (row)
    const int sc = (t & 1) * 32;      // col-half within BK=64

    bf16x8 xp[4], wp[4];
#pragma unroll
    for (int i = 0; i < 4; ++i) {
        xp[i] = *(const bf16x8*)(Xsrc + (size_t)(bm * 128 + sm) * 256 + sc + i * 8);
        wp[i] = *(const bf16x8*)(Wsrc + (size_t)(bn * 128 + sm) * 256 + sc + i * 8);
    }

    for (int kt = 0; kt < 4; ++kt) {
#pragma unroll
        for (int i = 0; i < 4; ++i) {
            *(bf16x8*)(Xs + sm * 72 + sc + i * 8) = xp[i];
            *(bf16x8*)(Ws + sm * 72 + sc + i * 8) = wp[i];
        }
        __syncthreads();

        if (kt < 3) {
#pragma unroll
            for (int i = 0; i < 4; ++i) {
                xp[i] = *(const bf16x8*)(Xsrc + (size_t)(bm * 128 + sm) * 256 + (kt + 1) * 64 + sc + i * 8);
                wp[i] = *(const bf16x8*)(Wsrc + (size_t)(bn * 128 + sm) * 256 + (kt + 1) * 64 + sc + i * 8);
            }
        }

#pragma unroll
        for (int ks = 0; ks < 2; ++ks) {
            bf16x8 a[4], b[4];
#pragma unroll
            for (int mt = 0; mt < 4; ++mt)
                a[mt] = *(const bf16x8*)(Xs + (rh + mt * 16 + l16) * 72 + ks * 32 + quad * 8);
#pragma unroll
            for (int nt = 0; nt < 4; ++nt)
                b[nt] = *(const bf16x8*)(Ws + (ch + nt * 16 + l16) * 72 + ks * 32 + quad * 8);
#pragma unroll
            for (int mt = 0; mt < 4; ++mt)
#pragma unroll
                for (int nt = 0; nt < 4; ++nt)
                    acc[mt][nt] = __builtin_amdgcn_mfma_f32_16x16x32_bf16(
                        a[mt], b[nt], acc[mt][nt], 0, 0, 0);
        }
        __syncthreads();
    }

#pragma unroll
    for (int nt = 0; nt < 4; ++nt) {
        int col = bn * 128 + ch + nt * 16 + l16;
        float bvv = bias[col];
#pragma unroll
        for (int mt = 0; mt < 4; ++mt) {
#pragma unroll
            for (int r = 0; r < 4; ++r) {
                int grow = bm * 128 + rh + mt * 16 + quad * 4 + r;
                float v = acc[mt][nt][r] + bvv;
                if (OUT_F32) {
                    ((float*)out)[(size_t)grow * 256 + col] = v;
                } else if (vmode) {
                    int b = grow >> 10, m = grow & 1023;
                    ((bf16*)out)[(size_t)b * 262144 + (size_t)col * 1024 + m] = (bf16)v;
                } else {
                    ((bf16*)out)[(size_t)grow * 256 + col] = (bf16)v;
                }
            }
        }
    }
}

// qkv: grid (256 bm, 6): y -> proj = y>>1, bn = y&1
__global__ __launch_bounds__(256, 2) void qkv_gemm(
    const bf16* __restrict__ Xb, const bf16* __restrict__ Wt,
    const float* __restrict__ bq, const float* __restrict__ bk,
    const float* __restrict__ bv,
    bf16* __restrict__ Qo, bf16* __restrict__ Ko, bf16* __restrict__ Vto)
{
    const int proj = blockIdx.y >> 1, bn = blockIdx.y & 1;
    const bf16* W = Wt + (size_t)proj * 65536;
    const float* bias = (proj == 0) ? bq : (proj == 1) ? bk : bv;
    void* out = (proj == 0) ? (void*)Qo : (proj == 1) ? (void*)Ko : (void*)Vto;
    gemm128_body<0>(Xb, W, bias, blockIdx.x, bn, out, proj == 2);
}

// oproj: grid (256 bm, 2 bn)
__global__ __launch_bounds__(256, 2) void oproj_gemm(
    const bf16* __restrict__ Aw, const bf16* __restrict__ Wo,
    const float* __restrict__ bo, float* __restrict__ out)
{
    gemm128_body<1>(Aw, Wo, bo, blockIdx.x, blockIdx.y, out, 0);
}

// ---------------------------------------------------------------------------
// Flash attention v6: 128 threads = 2 waves, 64 Q-rows per wave (mt=4).
// Halves DS-read traffic per output row vs 4-wave/32-row (K/V tile must be
// fully read by EVERY wave — fewer waves, more rows each, wins).
// LDS-staged K/V (round-4 verified), no-max softmax, P via wave-private LDS.
// Attended written in place over Q.
// ---------------------------------------------------------------------------
__global__ __launch_bounds__(128, 1) void flash_attn(
    const bf16* __restrict__ Qr, const bf16* __restrict__ K,
    const bf16* __restrict__ Vt, bf16* __restrict__ A)
{
    __shared__ bf16 Ks[32 * 264];      // [kv][c], pad 256->264   (16.9 KB)
    __shared__ bf16 Vs[256 * 40];      // [c][kv], pad 32->40     (20.5 KB)
    __shared__ bf16 Ps[2 * 64 * 40];   // per-wave P [64][32] pad (10.2 KB)

    const int t    = threadIdx.x;
    const int lane = t & 63, wv = t >> 6;        // wv in {0,1}
    const int quad = lane >> 4, l16 = lane & 15;
    const int b  = blockIdx.x;   // 0..31 (fastest -> XCD = b % 8)
    const int qt = blockIdx.y;   // 0..7

    // Q fragments: 64 rows/wave, A[m=lane&15][k=quad*8+j]   (128 VGPR)
    bf16x8 qf[4][8];
#pragma unroll
    for (int mt = 0; mt < 4; ++mt) {
        const size_t qrow = (size_t)b * 1024 + qt * 128 + wv * 64 + mt * 16 + l16;
#pragma unroll
        for (int ks = 0; ks < 8; ++ks)
            qf[mt][ks] = *(const bf16x8*)(Qr + qrow * 256 + ks * 32 + quad * 8);
    }

    const f32x4 zero = {0.0f, 0.0f, 0.0f, 0.0f};
    f32x4 o[4][16];                               // 256 VGPR accumulator
#pragma unroll
    for (int mt = 0; mt < 4; ++mt)
        for (int n = 0; n < 16; ++n) o[mt][n] = zero;
    float lst[4][4];
#pragma unroll
    for (int mt = 0; mt < 4; ++mt)
        for (int r = 0; r < 4; ++r) lst[mt][r] = 0.0f;

    bf16* Pw = Ps + wv * 64 * 40;

    // staging split across 128 threads:
    // K: thread -> row t>>2 (32 rows), 8 chunks of 8 elems at (t&3)*64 + i*8
    // V: thread -> c-rows t and t+128, 4 chunks of 8 kv each
    const int kkv = t >> 2, kc = (t & 3) * 64;

    for (int j = 0; j < 32; ++j) {
        // ---- stage K [32][256] and Vt [256][32]
#pragma unroll
        for (int i = 0; i < 8; ++i)
            *(bf16x8*)(Ks + kkv * 264 + kc + i * 8) =
                *(const bf16x8*)(K + (size_t)(b * 1024 + j * 32 + kkv) * 256 + kc + i * 8);
#pragma unroll
        for (int p = 0; p < 2; ++p) {
            int c = t + p * 128;
#pragma unroll
            for (int i = 0; i < 4; ++i)
                *(bf16x8*)(Vs + c * 40 + i * 8) =
                    *(const bf16x8*)(Vt + (size_t)b * 262144 + (size_t)c * 1024 + j * 32 + i * 8);
        }
        __syncthreads();

        // ---- S = Q K^T : each kf frag feeds 4 MFMAs (mt reuse)
        f32x4 s[4][2];
#pragma unroll
        for (int mt = 0; mt < 4; ++mt) { s[mt][0] = zero; s[mt][1] = zero; }
#pragma unroll
        for (int ks = 0; ks < 8; ++ks) {
#pragma unroll
            for (int n = 0; n < 2; ++n) {
                bf16x8 kf = *(const bf16x8*)(Ks + (n * 16 + l16) * 264 + ks * 32 + quad * 8);
#pragma unroll
                for (int mt = 0; mt < 4; ++mt)
                    s[mt][n] = __builtin_amdgcn_mfma_f32_16x16x32_bf16(
                        qf[mt][ks], kf, s[mt][n], 0, 0, 0);
            }
        }

        // ---- no-max softmax: p = exp2(s*SM_C); per-lane partial l
#pragma unroll
        for (int mt = 0; mt < 4; ++mt)
#pragma unroll
            for (int n = 0; n < 2; ++n)
#pragma unroll
                for (int r = 0; r < 4; ++r) {
                    float pv = __builtin_amdgcn_exp2f(s[mt][n][r] * SM_C);
                    lst[mt][r] += pv;
                    Pw[(mt * 16 + quad * 4 + r) * 40 + n * 16 + l16] = (bf16)pv;
                }

        // ---- P: wave-private LDS round-trip (C-layout -> A-layout)
        bf16x8 af[4];
#pragma unroll
        for (int mt = 0; mt < 4; ++mt)
            af[mt] = *(const bf16x8*)(Pw + (mt * 16 + l16) * 40 + quad * 8);

        // ---- O += P V : each vf frag feeds 4 MFMAs
#pragma unroll
        for (int n = 0; n < 16; ++n) {
            bf16x8 vf = *(const bf16x8*)(Vs + (n * 16 + l16) * 40 + quad * 8);
#pragma unroll
            for (int mt = 0; mt < 4; ++mt)
                o[mt][n] = __builtin_amdgcn_mfma_f32_16x16x32_bf16(
                    af[mt], vf, o[mt][n], 0, 0, 0);
        }
        __syncthreads();
    }

    // ---- epilogue: reduce l across 16-lane col group, normalize, store
#pragma unroll
    for (int mt = 0; mt < 4; ++mt) {
#pragma unroll
        for (int r = 0; r < 4; ++r) {
            float l = lst[mt][r];
            for (int off = 1; off < 16; off <<= 1)
                l += __shfl_xor(l, off, 64);
            float inv = 1.0f / l;
            size_t grow = (size_t)b * 1024 + qt * 128 + wv * 64 + mt * 16 + quad * 4 + r;
#pragma unroll
            for (int n = 0; n < 16; ++n)
                A[grow * 256 + n * 16 + l16] = (bf16)(o[mt][n][r] * inv);
        }
    }
}

// ---------------------------------------------------------------------------
extern "C" void kernel_launch(void* const* d_in, const int* in_sizes, int n_in,
                              void* d_out, int out_size, void* d_ws, size_t ws_size,
                              hipStream_t stream)
{
    (void)in_sizes; (void)n_in; (void)out_size; (void)ws_size;
    const float* X  = (const float*)d_in[0];
    const float* Wq = (const float*)d_in[1];
    const float* bq = (const float*)d_in[2];
    const float* Wk = (const float*)d_in[3];
    const float* bk = (const float*)d_in[4];
    const float* Wv = (const float*)d_in[5];
    const float* bv = (const float*)d_in[6];
    const float* Wo = (const float*)d_in[7];
    const float* bo = (const float*)d_in[8];
    float* out = (float*)d_out;

    const size_t NTOK = (size_t)32768 * 256;

    bf16* Xb = (bf16*)d_out;       // scratch in d_out, dead before final write
    bf16* Wt  = (bf16*)d_ws;
    bf16* Qw  = (bf16*)d_ws + 262144;
    bf16* Kw  = Qw + NTOK;
    bf16* Vtw = Kw + NTOK;

    cvt_x      <<<4096, 256, 0, stream>>>(X, Xb);
    transpose_w<<<dim3(16, 4), 256, 0, stream>>>(Wq, Wk, Wv, Wo, Wt);
    qkv_gemm   <<<dim3(256, 6), 256, 0, stream>>>(Xb, Wt, bq, bk, bv, Qw, Kw, Vtw);
    flash_attn <<<dim3(32, 8),  128, 0, stream>>>(Qw, Kw, Vtw, Qw);  // in-place
    oproj_gemm <<<dim3(256, 2), 256, 0, stream>>>(Qw, Wt + 3 * 65536, bo, out);
}

// Round 9
// 242.740 us; speedup vs baseline: 1.3875x; 1.3875x over previous
//
#include <hip/hip_runtime.h>
#include <hip/hip_bf16.h>

typedef __bf16 bf16;
typedef __bf16 bf16x8 __attribute__((ext_vector_type(8)));
typedef float f32x4 __attribute__((ext_vector_type(4)));

// (1/16) * log2(e): softmax scale folded into exp2
#define SM_C 0.09016994374947424f

// ---------------------------------------------------------------------------
// prep (fused): blocks 0..4095 convert X f32->bf16; blocks 4096..4159
// transpose W [k][n] f32 -> Wt[mat][n][k] bf16 via LDS tiles.
// ---------------------------------------------------------------------------
__global__ __launch_bounds__(256) void prep(
    const float* __restrict__ X, bf16* __restrict__ Xb,
    const float* __restrict__ Wq, const float* __restrict__ Wk,
    const float* __restrict__ Wv, const float* __restrict__ Wo,
    bf16* __restrict__ Wt)
{
    __shared__ bf16 Ls[64][72];
    const int t = threadIdx.x;
    if (blockIdx.x < 4096) {
        int i = blockIdx.x * 256 + t;
        const float* p = X + (size_t)i * 8;
        f32x4 a = *(const f32x4*)p, b = *(const f32x4*)(p + 4);
        bf16x8 r;
#pragma unroll
        for (int j = 0; j < 4; ++j) { r[j] = (bf16)a[j]; r[j + 4] = (bf16)b[j]; }
        *(bf16x8*)(Xb + (size_t)i * 8) = r;
        return;
    }
    const int bx = blockIdx.x - 4096;       // 0..63
    const int m = bx >> 4;                  // matrix 0..3
    const int tk = ((bx & 15) >> 2) * 64, tn = (bx & 3) * 64;
    const float* W = (m == 0) ? Wq : (m == 1) ? Wk : (m == 2) ? Wv : Wo;
    const int col = (t & 15) * 4, row = t >> 4;
#pragma unroll
    for (int p = 0; p < 4; ++p) {
        f32x4 v = *(const f32x4*)(W + (size_t)(tk + row + p * 16) * 256 + tn + col);
#pragma unroll
        for (int i = 0; i < 4; ++i) Ls[row + p * 16][col + i] = (bf16)v[i];
    }
    __syncthreads();
    const int kc = (t & 7) * 8, nr = t >> 3;
#pragma unroll
    for (int p = 0; p < 2; ++p) {
        bf16x8 r;
#pragma unroll
        for (int i = 0; i < 8; ++i) r[i] = Ls[kc + i][nr + p * 32];
        *(bf16x8*)(Wt + (size_t)m * 65536 + (size_t)(tn + nr + p * 32) * 256 + tk + kc) = r;
    }
}

// ---------------------------------------------------------------------------
// 128x128-tile GEMM core: 4 waves, each a 64x64 quadrant (4x4 16x16 frags).
// ---------------------------------------------------------------------------
template <int OUT_F32>
__device__ void gemm128_body(
    const bf16* __restrict__ Xsrc, const bf16* __restrict__ Wsrc,
    const float* __restrict__ bias, int bm, int bn,
    void* __restrict__ out, int vmode)
{
    __shared__ bf16 Xs[128 * 72];
    __shared__ bf16 Ws[128 * 72];

    const int t    = threadIdx.x;
    const int lane = t & 63, wv = t >> 6;
    const int quad = lane >> 4, l16 = lane & 15;
    const int rh = (wv >> 1) * 64;
    const int ch = (wv & 1) * 64;

    const f32x4 zero = {0.0f, 0.0f, 0.0f, 0.0f};
    f32x4 acc[4][4];
#pragma unroll
    for (int i = 0; i < 4; ++i)
        for (int j = 0; j < 4; ++j) acc[i][j] = zero;

    const int sm = t >> 1;
    const int sc = (t & 1) * 32;

    bf16x8 xp[4], wp[4];
#pragma unroll
    for (int i = 0; i < 4; ++i) {
        xp[i] = *(const bf16x8*)(Xsrc + (size_t)(bm * 128 + sm) * 256 + sc + i * 8);
        wp[i] = *(const bf16x8*)(Wsrc + (size_t)(bn * 128 + sm) * 256 + sc + i * 8);
    }

    for (int kt = 0; kt < 4; ++kt) {
#pragma unroll
        for (int i = 0; i < 4; ++i) {
            *(bf16x8*)(Xs + sm * 72 + sc + i * 8) = xp[i];
            *(bf16x8*)(Ws + sm * 72 + sc + i * 8) = wp[i];
        }
        __syncthreads();

        if (kt < 3) {
#pragma unroll
            for (int i = 0; i < 4; ++i) {
                xp[i] = *(const bf16x8*)(Xsrc + (size_t)(bm * 128 + sm) * 256 + (kt + 1) * 64 + sc + i * 8);
                wp[i] = *(const bf16x8*)(Wsrc + (size_t)(bn * 128 + sm) * 256 + (kt + 1) * 64 + sc + i * 8);
            }
        }

#pragma unroll
        for (int ks = 0; ks < 2; ++ks) {
            bf16x8 a[4], b[4];
#pragma unroll
            for (int mt = 0; mt < 4; ++mt)
                a[mt] = *(const bf16x8*)(Xs + (rh + mt * 16 + l16) * 72 + ks * 32 + quad * 8);
#pragma unroll
            for (int nt = 0; nt < 4; ++nt)
                b[nt] = *(const bf16x8*)(Ws + (ch + nt * 16 + l16) * 72 + ks * 32 + quad * 8);
#pragma unroll
            for (int mt = 0; mt < 4; ++mt)
#pragma unroll
                for (int nt = 0; nt < 4; ++nt)
                    acc[mt][nt] = __builtin_amdgcn_mfma_f32_16x16x32_bf16(
                        a[mt], b[nt], acc[mt][nt], 0, 0, 0);
        }
        __syncthreads();
    }

#pragma unroll
    for (int nt = 0; nt < 4; ++nt) {
        int col = bn * 128 + ch + nt * 16 + l16;
        float bvv = bias[col];
#pragma unroll
        for (int mt = 0; mt < 4; ++mt) {
#pragma unroll
            for (int r = 0; r < 4; ++r) {
                int grow = bm * 128 + rh + mt * 16 + quad * 4 + r;
                float v = acc[mt][nt][r] + bvv;
                if (OUT_F32) {
                    ((float*)out)[(size_t)grow * 256 + col] = v;
                } else if (vmode) {
                    int b = grow >> 10, m = grow & 1023;
                    ((bf16*)out)[(size_t)b * 262144 + (size_t)col * 1024 + m] = (bf16)v;
                } else {
                    ((bf16*)out)[(size_t)grow * 256 + col] = (bf16)v;
                }
            }
        }
    }
}

__global__ __launch_bounds__(256, 2) void qkv_gemm(
    const bf16* __restrict__ Xb, const bf16* __restrict__ Wt,
    const float* __restrict__ bq, const float* __restrict__ bk,
    const float* __restrict__ bv,
    bf16* __restrict__ Qo, bf16* __restrict__ Ko, bf16* __restrict__ Vto)
{
    const int proj = blockIdx.y >> 1, bn = blockIdx.y & 1;
    const bf16* W = Wt + (size_t)proj * 65536;
    const float* bias = (proj == 0) ? bq : (proj == 1) ? bk : bv;
    void* out = (proj == 0) ? (void*)Qo : (proj == 1) ? (void*)Ko : (void*)Vto;
    gemm128_body<0>(Xb, W, bias, blockIdx.x, bn, out, proj == 2);
}

__global__ __launch_bounds__(256, 2) void oproj_gemm(
    const bf16* __restrict__ Aw, const bf16* __restrict__ Wo,
    const float* __restrict__ bo, float* __restrict__ out)
{
    gemm128_body<1>(Aw, Wo, bo, blockIdx.x, blockIdx.y, out, 0);
}

// ---------------------------------------------------------------------------
// Flash attention v9 "c-share": 256 threads = 4 waves.
// Wave w: rows rh=(w&1)*64 (64 Q-rows), output cols ch=(w>>1)*128 (half of C).
// QK^T computed redundantly by wave pairs (MFMA has slack); per-wave DS read
// drops to K 16KB + V 8KB per 64 rows. Accumulator o = 128 regs/wave — the
// round-4-proven shape the compiler auto-places in AGPRs (no spill, no asm).
// No-max softmax; attended written in place over Q.
// ---------------------------------------------------------------------------
__global__ __launch_bounds__(256, 1) void flash_attn(
    const bf16* __restrict__ Qr, const bf16* __restrict__ K,
    const bf16* __restrict__ Vt, bf16* __restrict__ A)
{
    __shared__ bf16 Ks[32 * 264];      // [kv][c], pad 256->264  (16.9 KB)
    __shared__ bf16 Vs[256 * 40];      // [c][kv], pad 32->40    (20.5 KB)
    __shared__ bf16 Ps[4 * 64 * 40];   // per-wave P [64][32]    (20.5 KB)

    const int t    = threadIdx.x;
    const int lane = t & 63, wv = t >> 6;
    const int quad = lane >> 4, l16 = lane & 15;
    const int rh = (wv & 1) * 64;        // row-half of the 128-row tile
    const int ch = (wv >> 1) * 128;      // col-half of C=256
    const int b  = blockIdx.x;   // 0..31 (fastest -> XCD = b % 8)
    const int qt = blockIdx.y;   // 0..7

    // Q fragments: 64 rows/wave, A[m=lane&15][k=quad*8+j]  (128 arch VGPR)
    bf16x8 qf[4][8];
#pragma unroll
    for (int mt = 0; mt < 4; ++mt) {
        const size_t qrow = (size_t)b * 1024 + qt * 128 + rh + mt * 16 + l16;
#pragma unroll
        for (int ks = 0; ks < 8; ++ks)
            qf[mt][ks] = *(const bf16x8*)(Qr + qrow * 256 + ks * 32 + quad * 8);
    }

    const f32x4 zero = {0.0f, 0.0f, 0.0f, 0.0f};
    f32x4 o[4][8];                     // 64 rows x 128 cols -> 128 regs (AGPR)
#pragma unroll
    for (int mt = 0; mt < 4; ++mt)
        for (int n = 0; n < 8; ++n) o[mt][n] = zero;
    float lst[4][4];
#pragma unroll
    for (int mt = 0; mt < 4; ++mt)
        for (int r = 0; r < 4; ++r) lst[mt][r] = 0.0f;

    bf16* Pw = Ps + wv * 64 * 40;

    // staging split across 256 threads:
    const int kkv = t >> 3, kc = (t & 7) * 32;   // K: row t>>3, 4 x b128

    for (int j = 0; j < 32; ++j) {
        // ---- stage K [32][256] and Vt [256][32] (full V; waves read halves)
#pragma unroll
        for (int i = 0; i < 4; ++i)
            *(bf16x8*)(Ks + kkv * 264 + kc + i * 8) =
                *(const bf16x8*)(K + (size_t)(b * 1024 + j * 32 + kkv) * 256 + kc + i * 8);
#pragma unroll
        for (int i = 0; i < 4; ++i)
            *(bf16x8*)(Vs + t * 40 + i * 8) =
                *(const bf16x8*)(Vt + (size_t)b * 262144 + (size_t)t * 1024 + j * 32 + i * 8);
        __syncthreads();

        // ---- S = Q K^T (full c): each kf frag feeds 4 MFMAs
        f32x4 s[4][2];
#pragma unroll
        for (int mt = 0; mt < 4; ++mt) { s[mt][0] = zero; s[mt][1] = zero; }
#pragma unroll
        for (int ks = 0; ks < 8; ++ks) {
#pragma unroll
            for (int n = 0; n < 2; ++n) {
                bf16x8 kf = *(const bf16x8*)(Ks + (n * 16 + l16) * 264 + ks * 32 + quad * 8);
#pragma unroll
                for (int mt = 0; mt < 4; ++mt)
                    s[mt][n] = __builtin_amdgcn_mfma_f32_16x16x32_bf16(
                        qf[mt][ks], kf, s[mt][n], 0, 0, 0);
            }
        }

        // ---- no-max softmax: p = exp2(s*SM_C); per-lane partial l
#pragma unroll
        for (int mt = 0; mt < 4; ++mt)
#pragma unroll
            for (int n = 0; n < 2; ++n)
#pragma unroll
                for (int r = 0; r < 4; ++r) {
                    float pv = __builtin_amdgcn_exp2f(s[mt][n][r] * SM_C);
                    lst[mt][r] += pv;
                    Pw[(mt * 16 + quad * 4 + r) * 40 + n * 16 + l16] = (bf16)pv;
                }

        // ---- P: wave-private LDS round-trip (C-layout -> A-layout)
        bf16x8 af[4];
#pragma unroll
        for (int mt = 0; mt < 4; ++mt)
            af[mt] = *(const bf16x8*)(Pw + (mt * 16 + l16) * 40 + quad * 8);

        // ---- O += P V over this wave's col-half (8 n-tiles)
#pragma unroll
        for (int n = 0; n < 8; ++n) {
            bf16x8 vf = *(const bf16x8*)(Vs + (ch + n * 16 + l16) * 40 + quad * 8);
#pragma unroll
            for (int mt = 0; mt < 4; ++mt)
                o[mt][n] = __builtin_amdgcn_mfma_f32_16x16x32_bf16(
                    af[mt], vf, o[mt][n], 0, 0, 0);
        }
        __syncthreads();
    }

    // ---- epilogue: reduce l across 16-lane col group, normalize, store
#pragma unroll
    for (int mt = 0; mt < 4; ++mt) {
#pragma unroll
        for (int r = 0; r < 4; ++r) {
            float l = lst[mt][r];
            for (int off = 1; off < 16; off <<= 1)
                l += __shfl_xor(l, off, 64);
            float inv = 1.0f / l;
            size_t grow = (size_t)b * 1024 + qt * 128 + rh + mt * 16 + quad * 4 + r;
#pragma unroll
            for (int n = 0; n < 8; ++n)
                A[grow * 256 + ch + n * 16 + l16] = (bf16)(o[mt][n][r] * inv);
        }
    }
}

// ---------------------------------------------------------------------------
extern "C" void kernel_launch(void* const* d_in, const int* in_sizes, int n_in,
                              void* d_out, int out_size, void* d_ws, size_t ws_size,
                              hipStream_t stream)
{
    (void)in_sizes; (void)n_in; (void)out_size; (void)ws_size;
    const float* X  = (const float*)d_in[0];
    const float* Wq = (const float*)d_in[1];
    const float* bq = (const float*)d_in[2];
    const float* Wk = (const float*)d_in[3];
    const float* bk = (const float*)d_in[4];
    const float* Wv = (const float*)d_in[5];
    const float* bv = (const float*)d_in[6];
    const float* Wo = (const float*)d_in[7];
    const float* bo = (const float*)d_in[8];
    float* out = (float*)d_out;

    const size_t NTOK = (size_t)32768 * 256;

    bf16* Xb = (bf16*)d_out;       // scratch in d_out, dead before final write
    bf16* Wt  = (bf16*)d_ws;
    bf16* Qw  = (bf16*)d_ws + 262144;
    bf16* Kw  = Qw + NTOK;
    bf16* Vtw = Kw + NTOK;

    prep       <<<4160, 256, 0, stream>>>(X, Xb, Wq, Wk, Wv, Wo, Wt);
    qkv_gemm   <<<dim3(256, 6), 256, 0, stream>>>(Xb, Wt, bq, bk, bv, Qw, Kw, Vtw);
    flash_attn <<<dim3(32, 8),  256, 0, stream>>>(Qw, Kw, Vtw, Qw);  // in-place
    oproj_gemm <<<dim3(256, 2), 256, 0, stream>>>(Qw, Wt + 3 * 65536, bo, out);
}